// Round 4
// baseline (174.729 us; speedup 1.0000x reference)
//
#include <hip/hip_runtime.h>
#include <hip/hip_bf16.h>
#include <stdint.h>

// Problem constants
#define B_  8
#define S_  1024
#define H_  1024
#define NH_ 16
#define HD_ 64
#define M_  (B_*S_)   // 8192 rows of hidden

using bf16x8 = __attribute__((ext_vector_type(8))) __bf16;
using f32x4  = __attribute__((ext_vector_type(4))) float;
using f32x16 = __attribute__((ext_vector_type(16))) float;
typedef int iv2 __attribute__((ext_vector_type(2)));

#define LOG2E 1.4426950408889634f

#if __has_builtin(__builtin_amdgcn_exp2f)
#define EXP2(x) __builtin_amdgcn_exp2f(x)
#else
#define EXP2(x) exp2f(x)
#endif

#define SBAR() asm volatile("s_barrier" ::: "memory")
#define WAITV(n) asm volatile("s_waitcnt vmcnt(" #n ")" ::: "memory")

// async global->LDS, 16B per lane; lds ptr must be wave-uniform (HW adds lane*16)
__device__ __forceinline__ void gload_lds16(const void* g, void* l) {
  __builtin_amdgcn_global_load_lds(
      (const __attribute__((address_space(1))) unsigned int*)g,
      (__attribute__((address_space(3))) unsigned int*)l, 16, 0, 0);
}

// pack two f32 -> one u32 of 2 bf16 (lo in bits 0-15)
__device__ __forceinline__ unsigned pack_bf16(float lo, float hi) {
  unsigned r;
  asm("v_cvt_pk_bf16_f32 %0, %1, %2" : "=v"(r) : "v"(lo), "v"(hi));
  return r;
}

// swap a.hi32lanes <-> b.lo32lanes
__device__ __forceinline__ void swapl32(unsigned& a, unsigned& b) {
#if __has_builtin(__builtin_amdgcn_permlane32_swap)
  iv2 r = __builtin_amdgcn_permlane32_swap((int)a, (int)b, false, false);
  a = (unsigned)r[0];
  b = (unsigned)r[1];
#else
  unsigned axc = (unsigned)__shfl_xor((int)a, 32);
  unsigned bxc = (unsigned)__shfl_xor((int)b, 32);
  int lane = threadIdx.x & 63;
  unsigned an = (lane < 32) ? a : bxc;
  unsigned bn = (lane < 32) ? axc : b;
  a = an; b = bn;
#endif
}

// ---------------------------------------------------------------------------
// fp32 -> bf16 cast, vectorized 8 elems/thread
// ---------------------------------------------------------------------------
__global__ void __launch_bounds__(256) cast_bf16_kernel(const float* __restrict__ in,
                                                        __bf16* __restrict__ out, int n8) {
  int i = blockIdx.x * blockDim.x + threadIdx.x;
  int stride = gridDim.x * blockDim.x;
  for (; i < n8; i += stride) {
    float4 f0 = ((const float4*)in)[2 * i];
    float4 f1 = ((const float4*)in)[2 * i + 1];
    bf16x8 o;
    o[0] = (__bf16)f0.x; o[1] = (__bf16)f0.y; o[2] = (__bf16)f0.z; o[3] = (__bf16)f0.w;
    o[4] = (__bf16)f1.x; o[5] = (__bf16)f1.y; o[6] = (__bf16)f1.z; o[7] = (__bf16)f1.w;
    ((bf16x8*)out)[i] = o;
  }
}

// ---------------------------------------------------------------------------
// QKV projection GEMM, deep-pipelined (T1..T5):
//   C = X @ W^T + b; fused N = 3072 (z = Wq/Wk/Wv).
//   BM=BN=256, BK=32, 8 waves (2M x 4N), per-wave 128x64 (8x4 frags 16x16).
//   LDS: 4 rotating K-tile slots per operand (A,B each 4 x 16KB = 128KB).
//   Block t: computes tile t (2 phases x 16 MFMA), stages tile t+3.
//   Counted vmcnt(8) at block boundaries (never 0 in steady state).
//   XOR swizzle: 64B rows, chunk ^= (row>>1)&3, applied both-sides.
// Outputs: z=0 -> Q [B,NH,S,HD] * (0.125*log2e) ; z=1 -> K ; z=2 -> V^T [B,NH,HD,S]
// ---------------------------------------------------------------------------
#define NTILE 32           // K / 32
#define ASLOT(s) (lds + (size_t)(s) * 16384)
#define BSLOT(s) (lds + 65536 + (size_t)(s) * 16384)

__global__ void __launch_bounds__(512, 2) qkv_gemm_kernel(
    const __bf16* __restrict__ X,
    const __bf16* __restrict__ Wq, const __bf16* __restrict__ Wk, const __bf16* __restrict__ Wv,
    const float* __restrict__ bq, const float* __restrict__ bk, const float* __restrict__ bv,
    __bf16* __restrict__ Qo, __bf16* __restrict__ Ko, __bf16* __restrict__ Vto) {
  extern __shared__ char lds[];  // 131072 bytes

  const int tid = threadIdx.x;
  const int lane = tid & 63, w = tid >> 6;
  const int l15 = lane & 15, g = lane >> 4;
  const int wm = w >> 2, wn = w & 3;

  // bijective XCD swizzle: 384 blocks, 48 per XCD
  const int bid = blockIdx.x;
  const int swz = (bid & 7) * 48 + (bid >> 3);
  const int tm = swz / 12, tn = swz % 12;
  const int bm0 = tm * 256;
  const int z = tn >> 2;
  const int nz0 = (tn & 3) * 256;

  const __bf16* Wz = (z == 0) ? Wq : ((z == 1) ? Wk : Wv);
  const float* bias = (z == 0) ? bq : ((z == 1) ? bk : bv);

  // ---- staging source pointers (pre-swizzled global source, rule 21)
  const int trow = tid >> 2, tc = tid & 3;
  const int ssw = tc ^ ((trow >> 1) & 3);  // same for row and row+128
  const char* pA0 = (const char*)X + ((size_t)(bm0 + trow) * H_ + ssw * 8) * 2;
  const char* pA1 = (const char*)X + ((size_t)(bm0 + trow + 128) * H_ + ssw * 8) * 2;
  const char* pB0 = (const char*)Wz + ((size_t)(nz0 + trow) * H_ + ssw * 8) * 2;
  const char* pB1 = (const char*)Wz + ((size_t)(nz0 + trow + 128) * H_ + ssw * 8) * 2;

  // ---- per-lane ds_read offsets: addr = slot + row*64 + ((g ^ sw)<<4), sw = (l15>>1)&3
  const int sw = (l15 >> 1) & 3;
  const int aoff = (wm * 128 + l15) * 64 + ((g ^ sw) << 4);
  const int boff = (wn * 64 + l15) * 64 + ((g ^ sw) << 4);

  f32x4 acc[8][4] = {};

  // ---- prologue: stage tiles 0,1,2 (4 rounds each; 1 load/thread/round)
#pragma unroll
  for (int t = 0; t < 3; ++t) {
    const size_t o = (size_t)t * 64;
    gload_lds16(pA0 + o, ASLOT(t) + w * 1024);
    gload_lds16(pA1 + o, ASLOT(t) + 8192 + w * 1024);
    gload_lds16(pB0 + o, BSLOT(t) + w * 1024);
    gload_lds16(pB1 + o, BSLOT(t) + 8192 + w * 1024);
  }
  WAITV(8);  // tile 0 landed (tiles 1,2 = 8 loads still in flight)
  SBAR();

  // ---- main loop: 32 K-tiles, 2 phases each
  for (int t = 0; t < NTILE; ++t) {
    const int s = t & 3;
    const char* As = ASLOT(s);
    const char* Bs = BSLOT(s);
    const bool st = (t + 3) < NTILE;
    const int s3 = (t + 3) & 3;
    const size_t o3 = (size_t)(t + 3) * 64;

    // ===== phase 0: A-frags 0-3, all B-frags; stage A-rounds of tile t+3
    bf16x8 a0 = *(const bf16x8*)(As + aoff);
    bf16x8 a1 = *(const bf16x8*)(As + aoff + 1024);
    bf16x8 a2 = *(const bf16x8*)(As + aoff + 2048);
    bf16x8 a3 = *(const bf16x8*)(As + aoff + 3072);
    bf16x8 b0 = *(const bf16x8*)(Bs + boff);
    bf16x8 b1 = *(const bf16x8*)(Bs + boff + 1024);
    bf16x8 b2 = *(const bf16x8*)(Bs + boff + 2048);
    bf16x8 b3 = *(const bf16x8*)(Bs + boff + 3072);
    if (st) {
      gload_lds16(pA0 + o3, ASLOT(s3) + w * 1024);
      gload_lds16(pA1 + o3, ASLOT(s3) + 8192 + w * 1024);
    }
    SBAR();
    __builtin_amdgcn_s_setprio(1);
    acc[0][0] = __builtin_amdgcn_mfma_f32_16x16x32_bf16(a0, b0, acc[0][0], 0, 0, 0);
    acc[0][1] = __builtin_amdgcn_mfma_f32_16x16x32_bf16(a0, b1, acc[0][1], 0, 0, 0);
    acc[0][2] = __builtin_amdgcn_mfma_f32_16x16x32_bf16(a0, b2, acc[0][2], 0, 0, 0);
    acc[0][3] = __builtin_amdgcn_mfma_f32_16x16x32_bf16(a0, b3, acc[0][3], 0, 0, 0);
    acc[1][0] = __builtin_amdgcn_mfma_f32_16x16x32_bf16(a1, b0, acc[1][0], 0, 0, 0);
    acc[1][1] = __builtin_amdgcn_mfma_f32_16x16x32_bf16(a1, b1, acc[1][1], 0, 0, 0);
    acc[1][2] = __builtin_amdgcn_mfma_f32_16x16x32_bf16(a1, b2, acc[1][2], 0, 0, 0);
    acc[1][3] = __builtin_amdgcn_mfma_f32_16x16x32_bf16(a1, b3, acc[1][3], 0, 0, 0);
    acc[2][0] = __builtin_amdgcn_mfma_f32_16x16x32_bf16(a2, b0, acc[2][0], 0, 0, 0);
    acc[2][1] = __builtin_amdgcn_mfma_f32_16x16x32_bf16(a2, b1, acc[2][1], 0, 0, 0);
    acc[2][2] = __builtin_amdgcn_mfma_f32_16x16x32_bf16(a2, b2, acc[2][2], 0, 0, 0);
    acc[2][3] = __builtin_amdgcn_mfma_f32_16x16x32_bf16(a2, b3, acc[2][3], 0, 0, 0);
    acc[3][0] = __builtin_amdgcn_mfma_f32_16x16x32_bf16(a3, b0, acc[3][0], 0, 0, 0);
    acc[3][1] = __builtin_amdgcn_mfma_f32_16x16x32_bf16(a3, b1, acc[3][1], 0, 0, 0);
    acc[3][2] = __builtin_amdgcn_mfma_f32_16x16x32_bf16(a3, b2, acc[3][2], 0, 0, 0);
    acc[3][3] = __builtin_amdgcn_mfma_f32_16x16x32_bf16(a3, b3, acc[3][3], 0, 0, 0);
    __builtin_amdgcn_s_setprio(0);
    SBAR();

    // ===== phase 1: A-frags 4-7 (reuse B); stage B-rounds of tile t+3
    bf16x8 a4 = *(const bf16x8*)(As + aoff + 4096);
    bf16x8 a5 = *(const bf16x8*)(As + aoff + 5120);
    bf16x8 a6 = *(const bf16x8*)(As + aoff + 6144);
    bf16x8 a7 = *(const bf16x8*)(As + aoff + 7168);
    if (st) {
      gload_lds16(pB0 + o3, BSLOT(s3) + w * 1024);
      gload_lds16(pB1 + o3, BSLOT(s3) + 8192 + w * 1024);
    }
    // boundary wait: ensure tile t+1 landed; newer loads (t+2,t+3) stay in flight
    if (t < NTILE - 3) { WAITV(8); }
    else if (t == NTILE - 3) { WAITV(4); }
    else { WAITV(0); }
    SBAR();
    __builtin_amdgcn_s_setprio(1);
    acc[4][0] = __builtin_amdgcn_mfma_f32_16x16x32_bf16(a4, b0, acc[4][0], 0, 0, 0);
    acc[4][1] = __builtin_amdgcn_mfma_f32_16x16x32_bf16(a4, b1, acc[4][1], 0, 0, 0);
    acc[4][2] = __builtin_amdgcn_mfma_f32_16x16x32_bf16(a4, b2, acc[4][2], 0, 0, 0);
    acc[4][3] = __builtin_amdgcn_mfma_f32_16x16x32_bf16(a4, b3, acc[4][3], 0, 0, 0);
    acc[5][0] = __builtin_amdgcn_mfma_f32_16x16x32_bf16(a5, b0, acc[5][0], 0, 0, 0);
    acc[5][1] = __builtin_amdgcn_mfma_f32_16x16x32_bf16(a5, b1, acc[5][1], 0, 0, 0);
    acc[5][2] = __builtin_amdgcn_mfma_f32_16x16x32_bf16(a5, b2, acc[5][2], 0, 0, 0);
    acc[5][3] = __builtin_amdgcn_mfma_f32_16x16x32_bf16(a5, b3, acc[5][3], 0, 0, 0);
    acc[6][0] = __builtin_amdgcn_mfma_f32_16x16x32_bf16(a6, b0, acc[6][0], 0, 0, 0);
    acc[6][1] = __builtin_amdgcn_mfma_f32_16x16x32_bf16(a6, b1, acc[6][1], 0, 0, 0);
    acc[6][2] = __builtin_amdgcn_mfma_f32_16x16x32_bf16(a6, b2, acc[6][2], 0, 0, 0);
    acc[6][3] = __builtin_amdgcn_mfma_f32_16x16x32_bf16(a6, b3, acc[6][3], 0, 0, 0);
    acc[7][0] = __builtin_amdgcn_mfma_f32_16x16x32_bf16(a7, b0, acc[7][0], 0, 0, 0);
    acc[7][1] = __builtin_amdgcn_mfma_f32_16x16x32_bf16(a7, b1, acc[7][1], 0, 0, 0);
    acc[7][2] = __builtin_amdgcn_mfma_f32_16x16x32_bf16(a7, b2, acc[7][2], 0, 0, 0);
    acc[7][3] = __builtin_amdgcn_mfma_f32_16x16x32_bf16(a7, b3, acc[7][3], 0, 0, 0);
    __builtin_amdgcn_s_setprio(0);
    SBAR();
  }

  // ---- epilogue
#pragma unroll
  for (int nf = 0; nf < 4; ++nf) {
    const int ng = tn * 256 + wn * 64 + nf * 16 + l15;  // fused n in [0,3072)
    const int nzn = ng & 1023;
    const float bs = bias[nzn];
    const int nh = nzn >> 6, d = nzn & 63;
#pragma unroll
    for (int mf = 0; mf < 8; ++mf) {
#pragma unroll
      for (int r = 0; r < 4; ++r) {
        const int m = bm0 + wm * 128 + mf * 16 + 4 * g + r;
        const int bb = m >> 10, sI = m & 1023;
        const float v = acc[mf][nf][r] + bs;
        if (z == 0) {
          Qo[(((size_t)bb * NH_ + nh) * S_ + sI) * HD_ + d] = (__bf16)(v * (0.125f * LOG2E));
        } else if (z == 1) {
          Ko[(((size_t)bb * NH_ + nh) * S_ + sI) * HD_ + d] = (__bf16)v;
        } else {
          Vto[(((size_t)bb * NH_ + nh) * HD_ + d) * S_ + sI] = (__bf16)v;
        }
      }
    }
  }
}

// ---------------------------------------------------------------------------
// Flash attention, 8-wave 32x32 structure (unchanged from round 2 — validated)
// ---------------------------------------------------------------------------
#define CROW(r, hi) (((r) & 3) + 8 * ((r) >> 2) + 4 * (hi))

__global__ void __launch_bounds__(512) attn_kernel(
    const __bf16* __restrict__ Q,   // [128][1024][64]
    const __bf16* __restrict__ K,   // [128][1024][64]
    const __bf16* __restrict__ Vt,  // [128][64][1024]
    float* __restrict__ Out) {      // [8][1024][1024]
  __shared__ __align__(16) char Ksm[8192];
  __shared__ __align__(16) char Vsm[8192];
  __shared__ __align__(16) float stat_lds[512];

  const int tid = threadIdx.x, lane = tid & 63, w = tid >> 6;
  const int l31 = lane & 31, hi = lane >> 5;
  const int head = blockIdx.y;
  const int bb = head >> 4, nh = head & 15;
  const int qw = blockIdx.x * 256 + w * 32;

  const char* Qh = (const char*)(Q + (size_t)head * S_ * HD_);
  const char* Kh = (const char*)(K + (size_t)head * S_ * HD_);
  const char* Vh = (const char*)(Vt + (size_t)head * S_ * HD_);

  bf16x8 qf[4];
#pragma unroll
  for (int slot = 0; slot < 4; ++slot)
    qf[slot] = *reinterpret_cast<const bf16x8*>(
        Qh + (size_t)(qw + l31) * 128 + slot * 32 + hi * 16);

  float m_run = -1e30f, l_run = 0.0f;
  f32x16 accO[2] = {};

  for (int kv = 0; kv < S_; kv += 64) {
    __syncthreads();
    {
      int q = tid * 16;
      int row = q >> 7;
      int inrow = (q & 127) ^ ((row & 7) << 4);
      gload_lds16(Kh + (size_t)(kv + row) * 128 + inrow, Ksm + w * 1024);
      gload_lds16(Vh + (size_t)row * 2048 + kv * 2 + inrow, Vsm + w * 1024);
    }
    __syncthreads();

    f32x16 s0 = {}, s1 = {};
#pragma unroll
    for (int slot = 0; slot < 4; ++slot) {
      int c0 = slot * 2 + hi;
      int r0 = l31;
      bf16x8 k0 = *reinterpret_cast<const bf16x8*>(Ksm + r0 * 128 + ((c0 ^ (r0 & 7)) << 4));
      int r1 = 32 + l31;
      bf16x8 k1 = *reinterpret_cast<const bf16x8*>(Ksm + r1 * 128 + ((c0 ^ (r1 & 7)) << 4));
      s0 = __builtin_amdgcn_mfma_f32_32x32x16_bf16(k0, qf[slot], s0, 0, 0, 0);
      s1 = __builtin_amdgcn_mfma_f32_32x32x16_bf16(k1, qf[slot], s1, 0, 0, 0);
    }

    float mx = -1e30f;
#pragma unroll
    for (int r = 0; r < 16; ++r) mx = fmaxf(mx, fmaxf(s0[r], s1[r]));
    mx = fmaxf(mx, __shfl_xor(mx, 32));
    float mnew = fmaxf(m_run, mx);
    float corr = EXP2(m_run - mnew);
    float sum = 0.0f;
#pragma unroll
    for (int r = 0; r < 16; ++r) {
      float p0 = EXP2(s0[r] - mnew); s0[r] = p0; sum += p0;
      float p1 = EXP2(s1[r] - mnew); s1[r] = p1; sum += p1;
    }
    sum += __shfl_xor(sum, 32);
    l_run = l_run * corr + sum;
    m_run = mnew;

    stat_lds[w * 64 + lane] = corr;
    f32x4 c4[4];
#pragma unroll
    for (int rq = 0; rq < 4; ++rq)
      c4[rq] = *reinterpret_cast<const f32x4*>(&stat_lds[w * 64 + rq * 8 + hi * 4]);
#pragma unroll
    for (int r = 0; r < 16; ++r) {
      float cr = c4[r >> 2][r & 3];
      accO[0][r] *= cr;
      accO[1][r] *= cr;
    }

    bf16x8 pa[4];
#define BUILD_PA(T, rb)                                                     \
    {                                                                       \
      unsigned x1 = pack_bf16(T[rb + 0], T[rb + 1]);                        \
      unsigned x2 = pack_bf16(T[rb + 2], T[rb + 3]);                        \
      unsigned y1 = pack_bf16(T[rb + 4], T[rb + 5]);                        \
      unsigned y2 = pack_bf16(T[rb + 6], T[rb + 7]);                        \
      swapl32(x1, y1);                                                      \
      swapl32(x2, y2);                                                      \
      union { unsigned u[4]; bf16x8 v; } cvt;                               \
      cvt.u[0] = x1; cvt.u[1] = x2; cvt.u[2] = y1; cvt.u[3] = y2;           \
      pa_out = cvt.v;                                                       \
    }
    {
      bf16x8 pa_out;
      BUILD_PA(s0, 0) pa[0] = pa_out;
      BUILD_PA(s0, 8) pa[1] = pa_out;
      BUILD_PA(s1, 0) pa[2] = pa_out;
      BUILD_PA(s1, 8) pa[3] = pa_out;
    }

#pragma unroll
    for (int ks = 0; ks < 4; ++ks) {
#pragma unroll
      for (int dt = 0; dt < 2; ++dt) {
        int rd = dt * 32 + l31;
        int ck = ks * 2 + hi;
        bf16x8 vb = *reinterpret_cast<const bf16x8*>(Vsm + rd * 128 + ((ck ^ (rd & 7)) << 4));
        accO[dt] = __builtin_amdgcn_mfma_f32_32x32x16_bf16(pa[ks], vb, accO[dt], 0, 0, 0);
      }
    }
  }

  stat_lds[w * 64 + lane] = 1.0f / l_run;
  f32x4 li4[4];
#pragma unroll
  for (int rq = 0; rq < 4; ++rq)
    li4[rq] = *reinterpret_cast<const f32x4*>(&stat_lds[w * 64 + rq * 8 + hi * 4]);

  float* Ob = Out + (size_t)bb * S_ * H_ + (size_t)nh * HD_;
#pragma unroll
  for (int r = 0; r < 16; ++r) {
    int qabs = qw + CROW(r, hi);
    float li = li4[r >> 2][r & 3];
#pragma unroll
    for (int dt = 0; dt < 2; ++dt) {
      int d = dt * 32 + l31;
      Ob[(size_t)qabs * H_ + d] = accO[dt][r] * li;
    }
  }
}

// ---------------------------------------------------------------------------
extern "C" void kernel_launch(void* const* d_in, const int* in_sizes, int n_in,
                              void* d_out, int out_size, void* d_ws, size_t ws_size,
                              hipStream_t stream) {
  const float* hs = (const float*)d_in[0];
  const float* Wq = (const float*)d_in[1];
  const float* bq = (const float*)d_in[2];
  const float* Wk = (const float*)d_in[3];
  const float* bk = (const float*)d_in[4];
  const float* Wv = (const float*)d_in[5];
  const float* bv = (const float*)d_in[6];
  float* out = (float*)d_out;
  char* ws = (char*)d_ws;

  size_t off = 0;
  __bf16* Xb  = (__bf16*)(ws + off); off += (size_t)M_ * H_ * 2;
  __bf16* Wqb = (__bf16*)(ws + off); off += (size_t)H_ * H_ * 2;
  __bf16* Wkb = (__bf16*)(ws + off); off += (size_t)H_ * H_ * 2;
  __bf16* Wvb = (__bf16*)(ws + off); off += (size_t)H_ * H_ * 2;
  __bf16* Qb  = (__bf16*)(ws + off); off += (size_t)M_ * H_ * 2;
  __bf16* Kb  = (__bf16*)(ws + off); off += (size_t)M_ * H_ * 2;
  __bf16* Vtb = (__bf16*)(ws + off); off += (size_t)M_ * H_ * 2;

  // allow 128 KiB dynamic LDS (harmless if already permitted; host-side,
  // no stream interaction -> graph-capture safe, deterministic)
  (void)hipFuncSetAttribute((const void*)qkv_gemm_kernel,
                            hipFuncAttributeMaxDynamicSharedMemorySize, 131072);

  cast_bf16_kernel<<<4096, 256, 0, stream>>>(hs, Xb, M_ * H_ / 8);
  cast_bf16_kernel<<<512, 256, 0, stream>>>(Wq, Wqb, H_ * H_ / 8);
  cast_bf16_kernel<<<512, 256, 0, stream>>>(Wk, Wkb, H_ * H_ / 8);
  cast_bf16_kernel<<<512, 256, 0, stream>>>(Wv, Wvb, H_ * H_ / 8);

  qkv_gemm_kernel<<<384, 512, 131072, stream>>>(
      Xb, Wqb, Wkb, Wvb, bq, bk, bv, Qb, Kb, Vtb);

  attn_kernel<<<dim3(S_ / 256, B_ * NH_), 512, 0, stream>>>(Qb, Kb, Vtb, out);
}

// Round 6
// 150.645 us; speedup vs baseline: 1.1599x; 1.1599x over previous
//
#include <hip/hip_runtime.h>
#include <hip/hip_bf16.h>
#include <stdint.h>

// Problem constants
#define B_  8
#define S_  1024
#define H_  1024
#define NH_ 16
#define HD_ 64
#define M_  (B_*S_)   // 8192 rows of hidden

using bf16x8 = __attribute__((ext_vector_type(8))) __bf16;
using f32x4  = __attribute__((ext_vector_type(4))) float;
using f32x16 = __attribute__((ext_vector_type(16))) float;
typedef int iv2 __attribute__((ext_vector_type(2)));

#define LOG2E 1.4426950408889634f

#if __has_builtin(__builtin_amdgcn_exp2f)
#define EXP2(x) __builtin_amdgcn_exp2f(x)
#else
#define EXP2(x) exp2f(x)
#endif

#define SBAR() asm volatile("s_barrier" ::: "memory")
#define WAITV(n) asm volatile("s_waitcnt vmcnt(" #n ")" ::: "memory")

// async global->LDS, 16B per lane; lds ptr must be wave-uniform (HW adds lane*16)
__device__ __forceinline__ void gload_lds16(const void* g, void* l) {
  __builtin_amdgcn_global_load_lds(
      (const __attribute__((address_space(1))) unsigned int*)g,
      (__attribute__((address_space(3))) unsigned int*)l, 16, 0, 0);
}

// pack two f32 -> one u32 of 2 bf16 (lo in bits 0-15)
__device__ __forceinline__ unsigned pack_bf16(float lo, float hi) {
  unsigned r;
  asm("v_cvt_pk_bf16_f32 %0, %1, %2" : "=v"(r) : "v"(lo), "v"(hi));
  return r;
}

// swap a.hi32lanes <-> b.lo32lanes
__device__ __forceinline__ void swapl32(unsigned& a, unsigned& b) {
#if __has_builtin(__builtin_amdgcn_permlane32_swap)
  iv2 r = __builtin_amdgcn_permlane32_swap((int)a, (int)b, false, false);
  a = (unsigned)r[0];
  b = (unsigned)r[1];
#else
  unsigned axc = (unsigned)__shfl_xor((int)a, 32);
  unsigned bxc = (unsigned)__shfl_xor((int)b, 32);
  int lane = threadIdx.x & 63;
  unsigned an = (lane < 32) ? a : bxc;
  unsigned bn = (lane < 32) ? axc : b;
  a = an; b = bn;
#endif
}

// ---------------------------------------------------------------------------
// fp32 -> bf16 casts. X: one launch. W's: one fused launch (3 equal segments
// of 2^17 vec8-chunks each; contiguous destination).
// ---------------------------------------------------------------------------
__global__ void __launch_bounds__(256) cast_bf16_kernel(const float* __restrict__ in,
                                                        __bf16* __restrict__ out, int n8) {
  int i = blockIdx.x * blockDim.x + threadIdx.x;
  int stride = gridDim.x * blockDim.x;
  for (; i < n8; i += stride) {
    float4 f0 = ((const float4*)in)[2 * i];
    float4 f1 = ((const float4*)in)[2 * i + 1];
    bf16x8 o;
    o[0] = (__bf16)f0.x; o[1] = (__bf16)f0.y; o[2] = (__bf16)f0.z; o[3] = (__bf16)f0.w;
    o[4] = (__bf16)f1.x; o[5] = (__bf16)f1.y; o[6] = (__bf16)f1.z; o[7] = (__bf16)f1.w;
    ((bf16x8*)out)[i] = o;
  }
}

__global__ void __launch_bounds__(256) cast3_bf16_kernel(
    const float* __restrict__ s0, const float* __restrict__ s1,
    const float* __restrict__ s2, __bf16* __restrict__ dst) {
  int i = blockIdx.x * blockDim.x + threadIdx.x;  // [0, 3*131072)
  int seg = i >> 17, rem = i & 131071;
  const float* s = (seg == 0) ? s0 : ((seg == 1) ? s1 : s2);
  float4 f0 = ((const float4*)s)[2 * rem];
  float4 f1 = ((const float4*)s)[2 * rem + 1];
  bf16x8 o;
  o[0] = (__bf16)f0.x; o[1] = (__bf16)f0.y; o[2] = (__bf16)f0.z; o[3] = (__bf16)f0.w;
  o[4] = (__bf16)f1.x; o[5] = (__bf16)f1.y; o[6] = (__bf16)f1.z; o[7] = (__bf16)f1.w;
  ((bf16x8*)dst)[i] = o;
}

// ---------------------------------------------------------------------------
// QKV projection GEMM (exact round-2 structure — measured 90 us, 572 TF):
//   C = X @ W^T + b; 128x128 tile, BK=64, 4 waves (2x2), grid (64,8,3).
// Outputs: z=0 -> Q [B,NH,S,HD] * (0.125*log2e) ; z=1 -> K ; z=2 -> V^T
// ---------------------------------------------------------------------------
__global__ void __launch_bounds__(256) qkv_gemm_kernel(
    const __bf16* __restrict__ X,
    const __bf16* __restrict__ Wq, const __bf16* __restrict__ Wk, const __bf16* __restrict__ Wv,
    const float* __restrict__ bq, const float* __restrict__ bk, const float* __restrict__ bv,
    __bf16* __restrict__ Qo, __bf16* __restrict__ Ko, __bf16* __restrict__ Vto) {
  __shared__ __align__(16) char Asm[128 * 128];
  __shared__ __align__(16) char Bsm[128 * 128];

  const int tid = threadIdx.x;
  const int lane = tid & 63, w = tid >> 6;
  const int l15 = lane & 15, g = lane >> 4;
  const int wr = w >> 1, wc = w & 1;
  const int m0 = blockIdx.x * 128;
  const int n0 = blockIdx.y * 128;
  const int z = blockIdx.z;
  const __bf16* W = (z == 0) ? Wq : ((z == 1) ? Wk : Wv);
  const float* bias = (z == 0) ? bq : ((z == 1) ? bk : bv);

  f32x4 acc[4][4] = {};

  for (int kt = 0; kt < H_; kt += 64) {
    __syncthreads();
#pragma unroll
    for (int is = 0; is < 4; ++is) {
      int q = is * 4096 + tid * 16;
      int row = q >> 7;
      int inrow = (q & 127) ^ ((row & 7) << 4);
      const char* ga = (const char*)X + (size_t)(m0 + row) * (H_ * 2) + kt * 2 + inrow;
      const char* gb = (const char*)W + (size_t)(n0 + row) * (H_ * 2) + kt * 2 + inrow;
      gload_lds16(ga, Asm + is * 4096 + w * 1024);
      gload_lds16(gb, Bsm + is * 4096 + w * 1024);
    }
    __syncthreads();
#pragma unroll
    for (int ks = 0; ks < 2; ++ks) {
      bf16x8 a[4], b[4];
#pragma unroll
      for (int i = 0; i < 4; ++i) {
        int row = wr * 64 + i * 16 + l15;
        int chunk = (g + ks * 4) ^ (row & 7);
        a[i] = *reinterpret_cast<const bf16x8*>(Asm + row * 128 + chunk * 16);
      }
#pragma unroll
      for (int j = 0; j < 4; ++j) {
        int row = wc * 64 + j * 16 + l15;
        int chunk = (g + ks * 4) ^ (row & 7);
        b[j] = *reinterpret_cast<const bf16x8*>(Bsm + row * 128 + chunk * 16);
      }
#pragma unroll
      for (int i = 0; i < 4; ++i)
#pragma unroll
        for (int j = 0; j < 4; ++j)
          acc[i][j] = __builtin_amdgcn_mfma_f32_16x16x32_bf16(a[i], b[j], acc[i][j], 0, 0, 0);
    }
  }

#pragma unroll
  for (int i = 0; i < 4; ++i) {
#pragma unroll
    for (int j = 0; j < 4; ++j) {
      int n = n0 + wc * 64 + j * 16 + l15;
      float bs = bias[n];
      int nh = n >> 6, d = n & 63;
#pragma unroll
      for (int r = 0; r < 4; ++r) {
        int m = m0 + wr * 64 + i * 16 + 4 * g + r;
        int bb = m >> 10, s = m & 1023;
        float v = acc[i][j][r] + bs;
        if (z == 0) {
          Qo[(((size_t)bb * NH_ + nh) * S_ + s) * HD_ + d] = (__bf16)(v * (0.125f * LOG2E));
        } else if (z == 1) {
          Ko[(((size_t)bb * NH_ + nh) * S_ + s) * HD_ + d] = (__bf16)v;
        } else {
          Vto[(((size_t)bb * NH_ + nh) * HD_ + d) * S_ + s] = (__bf16)v;
        }
      }
    }
  }
}

// ---------------------------------------------------------------------------
// Flash attention, 8-wave 32x32 structure + K/V double-buffer:
//  - 2 LDS slots per operand; stage tile t+1 at start of iter t
//  - counted vmcnt(2) steady state (tile t's 2 loads retired; t+1's in flight)
//  - setprio(1) around MFMA clusters (T5)
// Slot-race audit: stage into slot s at iter t is ordered after the end-of-iter
// barrier of iter t-1 (last reader of slot s). Read of slot s at iter t is
// protected by WAITV + SBAR at iter t entry.
// ---------------------------------------------------------------------------
#define CROW(r, hi) (((r) & 3) + 8 * ((r) >> 2) + 4 * (hi))

__global__ void __launch_bounds__(512) attn_kernel(
    const __bf16* __restrict__ Q,   // [128][1024][64]
    const __bf16* __restrict__ K,   // [128][1024][64]
    const __bf16* __restrict__ Vt,  // [128][64][1024]
    float* __restrict__ Out) {      // [8][1024][1024]
  __shared__ __align__(16) char Ksm[2][8192];
  __shared__ __align__(16) char Vsm[2][8192];
  __shared__ __align__(16) float stat_lds[512];

  const int tid = threadIdx.x, lane = tid & 63, w = tid >> 6;
  const int l31 = lane & 31, hi = lane >> 5;
  const int head = blockIdx.y;
  const int bb = head >> 4, nh = head & 15;
  const int qw = blockIdx.x * 256 + w * 32;

  const char* Qh = (const char*)(Q + (size_t)head * S_ * HD_);
  const char* Kh = (const char*)(K + (size_t)head * S_ * HD_);
  const char* Vh = (const char*)(Vt + (size_t)head * S_ * HD_);

  // per-thread staging geometry (1 K-load + 1 V-load per tile)
  const int srow = (tid * 16) >> 7;               // 0..63
  const int sinrow = ((tid * 16) & 127) ^ ((srow & 7) << 4);

  bf16x8 qf[4];
#pragma unroll
  for (int slot = 0; slot < 4; ++slot)
    qf[slot] = *reinterpret_cast<const bf16x8*>(
        Qh + (size_t)(qw + l31) * 128 + slot * 32 + hi * 16);

  float m_run = -1e30f, l_run = 0.0f;
  f32x16 accO[2] = {};

  // prologue: stage tile 0 into slot 0
  gload_lds16(Kh + (size_t)srow * 128 + sinrow, Ksm[0] + w * 1024);
  gload_lds16(Vh + (size_t)srow * 2048 + sinrow, Vsm[0] + w * 1024);

  for (int t = 0; t < 16; ++t) {
    const int cur = t & 1;
    if (t < 15) {
      const int nxt = cur ^ 1;
      const size_t kvn = (size_t)(t + 1) * 64;
      gload_lds16(Kh + (size_t)(kvn + srow) * 128 + sinrow, Ksm[nxt] + w * 1024);
      gload_lds16(Vh + (size_t)srow * 2048 + kvn * 2 + sinrow, Vsm[nxt] + w * 1024);
      WAITV(2);   // tile t's 2 loads retired; tile t+1's stay in flight
    } else {
      WAITV(0);
    }
    SBAR();

    const char* Kc = Ksm[cur];
    const char* Vc = Vsm[cur];

    // ---- QK^T (swapped): s0 = keys 0..31, s1 = keys 32..63; col = q = l31
    f32x16 s0 = {}, s1 = {};
    __builtin_amdgcn_s_setprio(1);
#pragma unroll
    for (int slot = 0; slot < 4; ++slot) {
      int c0 = slot * 2 + hi;
      int r0 = l31;
      bf16x8 k0 = *reinterpret_cast<const bf16x8*>(Kc + r0 * 128 + ((c0 ^ (r0 & 7)) << 4));
      int r1 = 32 + l31;
      bf16x8 k1 = *reinterpret_cast<const bf16x8*>(Kc + r1 * 128 + ((c0 ^ (r1 & 7)) << 4));
      s0 = __builtin_amdgcn_mfma_f32_32x32x16_bf16(k0, qf[slot], s0, 0, 0, 0);
      s1 = __builtin_amdgcn_mfma_f32_32x32x16_bf16(k1, qf[slot], s1, 0, 0, 0);
    }
    __builtin_amdgcn_s_setprio(0);

    // ---- online softmax (exp2 domain)
    float mx = -1e30f;
#pragma unroll
    for (int r = 0; r < 16; ++r) mx = fmaxf(mx, fmaxf(s0[r], s1[r]));
    mx = fmaxf(mx, __shfl_xor(mx, 32));
    float mnew = fmaxf(m_run, mx);
    float corr = EXP2(m_run - mnew);
    float sum = 0.0f;
#pragma unroll
    for (int r = 0; r < 16; ++r) {
      float p0 = EXP2(s0[r] - mnew); s0[r] = p0; sum += p0;
      float p1 = EXP2(s1[r] - mnew); s1[r] = p1; sum += p1;
    }
    sum += __shfl_xor(sum, 32);
    l_run = l_run * corr + sum;
    m_run = mnew;

    // redistribute corr (lane-space q=l31) -> reg-space rows (per-wave region)
    stat_lds[w * 64 + lane] = corr;
    f32x4 c4[4];
#pragma unroll
    for (int rq = 0; rq < 4; ++rq)
      c4[rq] = *reinterpret_cast<const f32x4*>(&stat_lds[w * 64 + rq * 8 + hi * 4]);
#pragma unroll
    for (int r = 0; r < 16; ++r) {
      float cr = c4[r >> 2][r & 3];
      accO[0][r] *= cr;
      accO[1][r] *= cr;
    }

    // ---- P -> A-fragments (in-register, cvt_pk + permlane32_swap)
    bf16x8 pa[4];
#define BUILD_PA(T, rb)                                                     \
    {                                                                       \
      unsigned x1 = pack_bf16(T[rb + 0], T[rb + 1]);                        \
      unsigned x2 = pack_bf16(T[rb + 2], T[rb + 3]);                        \
      unsigned y1 = pack_bf16(T[rb + 4], T[rb + 5]);                        \
      unsigned y2 = pack_bf16(T[rb + 6], T[rb + 7]);                        \
      swapl32(x1, y1);                                                      \
      swapl32(x2, y2);                                                      \
      union { unsigned u[4]; bf16x8 v; } cvt;                               \
      cvt.u[0] = x1; cvt.u[1] = x2; cvt.u[2] = y1; cvt.u[3] = y2;           \
      pa_out = cvt.v;                                                       \
    }
    {
      bf16x8 pa_out;
      BUILD_PA(s0, 0) pa[0] = pa_out;
      BUILD_PA(s0, 8) pa[1] = pa_out;
      BUILD_PA(s1, 0) pa[2] = pa_out;
      BUILD_PA(s1, 8) pa[3] = pa_out;
    }

    // ---- PV: accO[dt] += P[q][16ks..] @ V[16ks..][dt*32 + l31]
    __builtin_amdgcn_s_setprio(1);
#pragma unroll
    for (int ks = 0; ks < 4; ++ks) {
#pragma unroll
      for (int dt = 0; dt < 2; ++dt) {
        int rd = dt * 32 + l31;
        int ck = ks * 2 + hi;
        bf16x8 vb = *reinterpret_cast<const bf16x8*>(Vc + rd * 128 + ((ck ^ (rd & 7)) << 4));
        accO[dt] = __builtin_amdgcn_mfma_f32_32x32x16_bf16(pa[ks], vb, accO[dt], 0, 0, 0);
      }
    }
    __builtin_amdgcn_s_setprio(0);

    SBAR();  // all waves done reading slot cur before it is re-staged next iter
  }

  // ---- epilogue
  stat_lds[w * 64 + lane] = 1.0f / l_run;
  f32x4 li4[4];
#pragma unroll
  for (int rq = 0; rq < 4; ++rq)
    li4[rq] = *reinterpret_cast<const f32x4*>(&stat_lds[w * 64 + rq * 8 + hi * 4]);

  float* Ob = Out + (size_t)bb * S_ * H_ + (size_t)nh * HD_;
#pragma unroll
  for (int r = 0; r < 16; ++r) {
    int qabs = qw + CROW(r, hi);
    float li = li4[r >> 2][r & 3];
#pragma unroll
    for (int dt = 0; dt < 2; ++dt) {
      int d = dt * 32 + l31;
      Ob[(size_t)qabs * H_ + d] = accO[dt][r] * li;
    }
  }
}

// ---------------------------------------------------------------------------
extern "C" void kernel_launch(void* const* d_in, const int* in_sizes, int n_in,
                              void* d_out, int out_size, void* d_ws, size_t ws_size,
                              hipStream_t stream) {
  const float* hs = (const float*)d_in[0];
  const float* Wq = (const float*)d_in[1];
  const float* bq = (const float*)d_in[2];
  const float* Wk = (const float*)d_in[3];
  const float* bk = (const float*)d_in[4];
  const float* Wv = (const float*)d_in[5];
  const float* bv = (const float*)d_in[6];
  float* out = (float*)d_out;
  char* ws = (char*)d_ws;

  size_t off = 0;
  __bf16* Xb  = (__bf16*)(ws + off); off += (size_t)M_ * H_ * 2;
  __bf16* Wqb = (__bf16*)(ws + off); off += (size_t)H_ * H_ * 2;
  __bf16* Wkb = (__bf16*)(ws + off); off += (size_t)H_ * H_ * 2;
  __bf16* Wvb = (__bf16*)(ws + off); off += (size_t)H_ * H_ * 2;
  __bf16* Qb  = (__bf16*)(ws + off); off += (size_t)M_ * H_ * 2;
  __bf16* Kb  = (__bf16*)(ws + off); off += (size_t)M_ * H_ * 2;
  __bf16* Vtb = (__bf16*)(ws + off); off += (size_t)M_ * H_ * 2;

  cast_bf16_kernel<<<4096, 256, 0, stream>>>(hs, Xb, M_ * H_ / 8);
  cast3_bf16_kernel<<<1536, 256, 0, stream>>>(Wq, Wk, Wv, Wqb);

  qkv_gemm_kernel<<<dim3(M_ / 128, H_ / 128, 3), 256, 0, stream>>>(
      Xb, Wqb, Wkb, Wvb, bq, bk, bv, Qb, Kb, Vtb);

  attn_kernel<<<dim3(S_ / 256, B_ * NH_), 512, 0, stream>>>(Qb, Kb, Vtb, out);
}